// Round 10
// baseline (95255.865 us; speedup 1.0000x reference)
//
#include <hip/hip_runtime.h>
#include <math.h>

#define B_ 32
#define T_ 512
#define D_ 1024
#define H_ 1024
#define L_ 4
#define NTICK (T_ + L_ - 1)    // 515
#define RP 17                  // reduce row pad (floats), proven R0/R7/R9
#define SMEM_FLOATS (512 * RP) // 34816 B; aliases staging tile xs[32][256]

typedef unsigned long long u64;

// Cross-XCD state access: agent-scope relaxed atomics (sc1) hit the MALL
// coherence point directly. No fences anywhere -> XCD L2s never invalidated.
__device__ __forceinline__ float4 load_state4(const float* p) {
    u64 a = __hip_atomic_load((const u64*)p,       __ATOMIC_RELAXED, __HIP_MEMORY_SCOPE_AGENT);
    u64 b = __hip_atomic_load((const u64*)(p + 2), __ATOMIC_RELAXED, __HIP_MEMORY_SCOPE_AGENT);
    float4 v;
    v.x = __uint_as_float((unsigned)(a & 0xffffffffu));
    v.y = __uint_as_float((unsigned)(a >> 32));
    v.z = __uint_as_float((unsigned)(b & 0xffffffffu));
    v.w = __uint_as_float((unsigned)(b >> 32));
    return v;
}

// Relaxed spin + s_sleep throttle; short timeout + always-release => no hang.
__device__ __forceinline__ void waitCount(const unsigned int* p, unsigned int target) {
    int c = 0;
    while (__hip_atomic_load(p, __ATOMIC_RELAXED, __HIP_MEMORY_SCOPE_AGENT) < target) {
        __builtin_amdgcn_s_sleep(16);
        if (++c > 20000) return;   // ~4 ms/tick cap
    }
}

// One K-tile of 256: barrier -> stage 32x256 into LDS -> barrier -> 32 b-rows
// x {2 ds_read_b128 + 8 FMA} against REGISTER-PINNED weights w[TILE][0..7].
// TILE is a literal -> all w[][] indexing is compile-time (rule-#20: runtime
// indexing would send w to scratch).
#define TILE_BODY(TILE)                                                         \
    do {                                                                        \
        constexpr int kof = (TILE & 3) << 8;                                    \
        const float*  src = (TILE < 4) ? xsrc : hrow;                           \
        const size_t  str = (TILE < 4) ? xstr : (size_t)H_;                     \
        const bool useAtomic = (TILE >= 4) || (layer != 0);                     \
        __syncthreads();                                                        \
        _Pragma("unroll")                                                       \
        for (int s4 = 0; s4 < 4; ++s4) {                                        \
            const int r = srow + (s4 << 3);                                     \
            const float* sp = &src[(size_t)r * str + kof + scol];               \
            float4 v = useAtomic ? load_state4(sp) : *(const float4*)sp;        \
            *(float4*)&xs[r][scol] = v;                                         \
        }                                                                       \
        __syncthreads();                                                        \
        _Pragma("unroll")                                                       \
        for (int b = 0; b < 32; ++b) {                                          \
            const float4 a0 = *(const float4*)&xs[b][kb];                       \
            const float4 a1 = *(const float4*)&xs[b][kb + 4];                   \
            acc[b] += a0.x * w[TILE][0] + a0.y * w[TILE][1]                     \
                    + a0.z * w[TILE][2] + a0.w * w[TILE][3]                     \
                    + a1.x * w[TILE][4] + a1.y * w[TILE][5]                     \
                    + a1.z * w[TILE][6] + a1.w * w[TILE][7];                    \
        }                                                                       \
    } while (0)

// Persistent kernel: 256 blocks (1/CU), 512 threads = 16 jj x 32 kslot.
// R10 change (single variable vs R9): the 64 weight floats each thread needs
// per tick are loaded ONCE into VGPRs before the tick loop (R9 counters: the
// per-tick weight re-fetch past L2 was 36.6 MB/tick ~= the whole tick time).
// Viable now because base VGPR=44 under __launch_bounds__(512,2) (256 budget);
// R1's attempt died on the 128-VGPR default cap.
__global__ __launch_bounds__(512, 2) void lnn_persist(
    const float* __restrict__ x,      // [B][T][D]
    const float* __restrict__ W_in,   // [L][D][H]
    const float* __restrict__ b_in,   // [L][H]
    const float* __restrict__ W_h,    // [L][H][H]
    const float* __restrict__ b_h,    // [L][H]
    const float* __restrict__ tau,    // [L][H]
    float* __restrict__ buf0,         // [L][B][H] state, tick-parity 0
    float* __restrict__ buf1,         // [L][B][H] state, tick-parity 1
    unsigned int* __restrict__ count) // [NTICK] lockstep counters
{
    const int tid   = threadIdx.x;
    const int layer = blockIdx.x >> 6;
    const int jbase = (blockIdx.x & 63) << 4;
    const int jj    = tid & 15;       // col within slice
    const int kslot = tid >> 4;       // 0..31
    const int jg    = jbase + jj;
    const int kb    = kslot << 3;

    __shared__ __align__(16) float smem[SMEM_FLOATS];
    float (*xs)[256] = (float(*)[256])smem;

    const float* Wl_in = W_in + (size_t)layer * D_ * H_;
    const float* Wl_h  = W_h  + (size_t)layer * H_ * H_;

    // ---- pin 64 weight floats/thread in VGPRs (loaded once, reused 512x) ----
    float w[8][8];
#pragma unroll
    for (int tl = 0; tl < 8; ++tl) {
        const float* wp = ((tl < 4) ? Wl_in : Wl_h) + (size_t)((tl & 3) * 256 + kb) * H_ + jg;
#pragma unroll
        for (int i = 0; i < 8; ++i) w[tl][i] = wp[(size_t)i * H_];
    }

    const float bias = b_in[layer * H_ + jg] + b_h[layer * H_ + jg];
    const float tv   = tau[layer * H_ + jg];

    for (int tick = 0; tick < NTICK; ++tick) {
        if (tid == 0 && tick > 0)
            waitCount(&count[tick - 1], 256u);
        __syncthreads();   // all threads ordered after the wait

        const int t = tick - layer;
        if (t >= 0 && t < T_) {
            const float* rb   = (tick & 1) ? buf0 : buf1;   // state at t-1
            float*       wb   = (tick & 1) ? buf1 : buf0;   // state at t
            const float* hrow = rb + (size_t)layer * B_ * H_;

            const float* xsrc; size_t xstr;
            if (layer == 0) { xsrc = x + (size_t)t * D_;                  xstr = (size_t)T_ * D_; }
            else            { xsrc = rb + (size_t)(layer - 1) * B_ * H_;  xstr = H_; }

            float acc[32];
#pragma unroll
            for (int i = 0; i < 32; ++i) acc[i] = 0.f;

            // staging role: e = s4*512 + tid -> row e>>6, float4-col e&63
            const int srow = tid >> 6;
            const int scol = (tid & 63) << 2;

            TILE_BODY(0); TILE_BODY(1); TILE_BODY(2); TILE_BODY(3);
            TILE_BODY(4); TILE_BODY(5); TILE_BODY(6); TILE_BODY(7);

            // ---- two-phase k-reduction through padded LDS (proven R0/R7/R9) ----
            float* wl = wb + (size_t)layer * B_ * H_;
#pragma unroll 1
            for (int p = 0; p < 2; ++p) {
                __syncthreads();   // previous LDS use complete
#pragma unroll
                for (int c = 0; c < 16; ++c)
                    smem[tid * RP + c] = acc[p * 16 + c];
                __syncthreads();
                if (tid < 256) {
                    const int c = tid >> 4;            // 0..15
                    const int b = c + p * 16;
                    float s = 0.f;
#pragma unroll
                    for (int ks = 0; ks < 32; ++ks)
                        s += smem[(jj + (ks << 4)) * RP + c];
                    const float dx   = tanhf(s + bias);
                    const float hold = __hip_atomic_load(&hrow[(size_t)b * H_ + jg],
                                                         __ATOMIC_RELAXED, __HIP_MEMORY_SCOPE_AGENT);
                    const float hn   = hold + (dx - hold) / tv;
                    __hip_atomic_store(&wl[(size_t)b * H_ + jg], hn,
                                       __ATOMIC_RELAXED, __HIP_MEMORY_SCOPE_AGENT);
                }
            }
        }

        // __syncthreads() drains every wave's vmem ops (s_waitcnt vmcnt(0)
        // before s_barrier) -> all sc1 stores at MALL before the release-add.
        __syncthreads();
        if (tid == 0)
            __hip_atomic_fetch_add(&count[tick], 1u,
                                   __ATOMIC_RELEASE, __HIP_MEMORY_SCOPE_AGENT);
    }
}

// out[b][o] = sum_k h3[b][k] * W_out[k][o] + b_out[o]   (validated rounds 0-9)
__global__ __launch_bounds__(256) void lnn_out(
    const float* __restrict__ H3,     // [B][H]
    const float* __restrict__ W_out,  // [H][O]
    const float* __restrict__ b_out,  // [O]
    float* __restrict__ out)          // [B][O]
{
    const int gid = blockIdx.x * 256 + threadIdx.x;  // 64 blocks -> 16384 threads
    const int jj  = gid & 1023;
    const int b2  = gid >> 10;                       // 0..15 -> rows b2, b2+16
    float acc0 = b_out[jj];
    float acc1 = b_out[jj];
    for (int k = 0; k < H_; ++k) {
        const float w = W_out[k * H_ + jj];
        acc0 += H3[b2 * H_ + k]        * w;
        acc1 += H3[(b2 + 16) * H_ + k] * w;
    }
    out[b2 * H_ + jj]        = acc0;
    out[(b2 + 16) * H_ + jj] = acc1;
}

extern "C" void kernel_launch(void* const* d_in, const int* in_sizes, int n_in,
                              void* d_out, int out_size, void* d_ws, size_t ws_size,
                              hipStream_t stream) {
    const float* x     = (const float*)d_in[0];
    const float* W_in  = (const float*)d_in[1];
    const float* b_in  = (const float*)d_in[2];
    const float* W_h   = (const float*)d_in[3];
    const float* b_h   = (const float*)d_in[4];
    const float* tau   = (const float*)d_in[5];
    const float* W_out = (const float*)d_in[6];
    const float* b_out = (const float*)d_in[7];

    const size_t stateElems = (size_t)L_ * B_ * H_;       // 131072 floats
    float* buf0 = (float*)d_ws;
    float* buf1 = buf0 + stateElems;
    unsigned int* count = (unsigned int*)(buf1 + stateElems);

    // zero state + lockstep counters (captured in graph -> reset every replay)
    (void)hipMemsetAsync(d_ws, 0,
                         2 * stateElems * sizeof(float) + NTICK * sizeof(unsigned int), stream);

    lnn_persist<<<256, 512, 0, stream>>>(x, W_in, b_in, W_h, b_h, tau, buf0, buf1, count);

    // h3 at t=511 computed at tick 514 -> write parity 514&1 = 0 -> buf0.
    // Kernel boundary provides coherence for these plain loads.
    const float* H3 = buf0 + 3 * (B_ * H_);
    lnn_out<<<64, 256, 0, stream>>>(H3, W_out, b_out, (float*)d_out);
}

// Round 12
// 92215.472 us; speedup vs baseline: 1.0330x; 1.0330x over previous
//
#include <hip/hip_runtime.h>
#include <math.h>

#define B_ 32
#define T_ 512
#define D_ 1024
#define H_ 1024
#define L_ 4
#define NTICK (T_ + L_ - 1)    // 515
#define RP 17                  // reduce row pad (floats), proven R0/R7/R9
#define SMEM_FLOATS (512 * RP) // 34816 B; aliases staging tile xs[32][256]

typedef unsigned long long u64;

// Cross-XCD state access: agent-scope relaxed atomics (sc1) hit the MALL
// coherence point directly. No fences anywhere -> XCD L2s never invalidated.
__device__ __forceinline__ float4 load_state4(const float* p) {
    u64 a = __hip_atomic_load((const u64*)p,       __ATOMIC_RELAXED, __HIP_MEMORY_SCOPE_AGENT);
    u64 b = __hip_atomic_load((const u64*)(p + 2), __ATOMIC_RELAXED, __HIP_MEMORY_SCOPE_AGENT);
    float4 v;
    v.x = __uint_as_float((unsigned)(a & 0xffffffffu));
    v.y = __uint_as_float((unsigned)(a >> 32));
    v.z = __uint_as_float((unsigned)(b & 0xffffffffu));
    v.w = __uint_as_float((unsigned)(b >> 32));
    return v;
}

// Relaxed spin + s_sleep throttle; short timeout + always-release => no hang.
__device__ __forceinline__ void waitCount(const unsigned int* p, unsigned int target) {
    int c = 0;
    while (__hip_atomic_load(p, __ATOMIC_RELAXED, __HIP_MEMORY_SCOPE_AGENT) < target) {
        __builtin_amdgcn_s_sleep(16);
        if (++c > 20000) return;   // ~4 ms/tick cap
    }
}

// One K-tile of 256: barrier -> stage 32x256 into LDS -> barrier -> 32 b-rows
// x {2 ds_read_b128 + 8 FMA} against REGISTER-PINNED weights w[TILE][0..7].
// TILE is a literal -> all w[][] indexing is compile-time (rule-#20).
#define TILE_BODY(TILE)                                                         \
    do {                                                                        \
        constexpr int kof = (TILE & 3) << 8;                                    \
        const float*  src = (TILE < 4) ? xsrc : hrow;                           \
        const size_t  str = (TILE < 4) ? xstr : (size_t)H_;                     \
        const bool useAtomic = (TILE >= 4) || (layer != 0);                     \
        __syncthreads();                                                        \
        _Pragma("unroll")                                                       \
        for (int s4 = 0; s4 < 4; ++s4) {                                        \
            const int r = srow + (s4 << 3);                                     \
            const float* sp = &src[(size_t)r * str + kof + scol];               \
            float4 v = useAtomic ? load_state4(sp) : *(const float4*)sp;        \
            *(float4*)&xs[r][scol] = v;                                         \
        }                                                                       \
        __syncthreads();                                                        \
        _Pragma("unroll")                                                       \
        for (int b = 0; b < 32; ++b) {                                          \
            const float4 a0 = *(const float4*)&xs[b][kb];                       \
            const float4 a1 = *(const float4*)&xs[b][kb + 4];                   \
            acc[b] += a0.x * w[TILE][0] + a0.y * w[TILE][1]                     \
                    + a0.z * w[TILE][2] + a0.w * w[TILE][3]                     \
                    + a1.x * w[TILE][4] + a1.y * w[TILE][5]                     \
                    + a1.z * w[TILE][6] + a1.w * w[TILE][7];                    \
        }                                                                       \
    } while (0)

// Persistent kernel: 256 blocks (1/CU), 512 threads = 16 jj x 32 kslot.
// R11/R12 change (single variable vs R10): occupancy declared in BACKEND units.
// R10 lesson: HIP __launch_bounds__ 2nd arg = min BLOCKS/CU (CUDA-style);
// (512,2) => 2 blocks x 8 waves / 4 SIMD = 4 waves/EU => 128-VGPR cap => the
// w[8][8] pin spilled (WRITE_SIZE 148 GB, 95 ms). amdgpu_waves_per_eu(2)
// states min 2 waves/EU directly => 256-VGPR budget => w[8][8]+acc[32] fit.
__global__ __launch_bounds__(512) __attribute__((amdgpu_waves_per_eu(2)))
void lnn_persist(
    const float* __restrict__ x,      // [B][T][D]
    const float* __restrict__ W_in,   // [L][D][H]
    const float* __restrict__ b_in,   // [L][H]
    const float* __restrict__ W_h,    // [L][H][H]
    const float* __restrict__ b_h,    // [L][H]
    const float* __restrict__ tau,    // [L][H]
    float* __restrict__ buf0,         // [L][B][H] state, tick-parity 0
    float* __restrict__ buf1,         // [L][B][H] state, tick-parity 1
    unsigned int* __restrict__ count) // [NTICK] lockstep counters
{
    const int tid   = threadIdx.x;
    const int layer = blockIdx.x >> 6;
    const int jbase = (blockIdx.x & 63) << 4;
    const int jj    = tid & 15;       // col within slice
    const int kslot = tid >> 4;       // 0..31
    const int jg    = jbase + jj;
    const int kb    = kslot << 3;

    __shared__ __align__(16) float smem[SMEM_FLOATS];
    float (*xs)[256] = (float(*)[256])smem;

    const float* Wl_in = W_in + (size_t)layer * D_ * H_;
    const float* Wl_h  = W_h  + (size_t)layer * H_ * H_;

    // ---- pin 64 weight floats/thread in VGPRs (loaded once, reused 512x) ----
    float w[8][8];
#pragma unroll
    for (int tl = 0; tl < 8; ++tl) {
        const float* wp = ((tl < 4) ? Wl_in : Wl_h) + (size_t)((tl & 3) * 256 + kb) * H_ + jg;
#pragma unroll
        for (int i = 0; i < 8; ++i) w[tl][i] = wp[(size_t)i * H_];
    }

    const float bias = b_in[layer * H_ + jg] + b_h[layer * H_ + jg];
    const float tv   = tau[layer * H_ + jg];

    for (int tick = 0; tick < NTICK; ++tick) {
        if (tid == 0 && tick > 0)
            waitCount(&count[tick - 1], 256u);
        __syncthreads();   // all threads ordered after the wait

        const int t = tick - layer;
        if (t >= 0 && t < T_) {
            const float* rb   = (tick & 1) ? buf0 : buf1;   // state at t-1
            float*       wb   = (tick & 1) ? buf1 : buf0;   // state at t
            const float* hrow = rb + (size_t)layer * B_ * H_;

            const float* xsrc; size_t xstr;
            if (layer == 0) { xsrc = x + (size_t)t * D_;                  xstr = (size_t)T_ * D_; }
            else            { xsrc = rb + (size_t)(layer - 1) * B_ * H_;  xstr = H_; }

            float acc[32];
#pragma unroll
            for (int i = 0; i < 32; ++i) acc[i] = 0.f;

            // staging role: e = s4*512 + tid -> row e>>6, float4-col e&63
            const int srow = tid >> 6;
            const int scol = (tid & 63) << 2;

            TILE_BODY(0); TILE_BODY(1); TILE_BODY(2); TILE_BODY(3);
            TILE_BODY(4); TILE_BODY(5); TILE_BODY(6); TILE_BODY(7);

            // ---- two-phase k-reduction through padded LDS (proven R0/R7/R9) ----
            float* wl = wb + (size_t)layer * B_ * H_;
#pragma unroll 1
            for (int p = 0; p < 2; ++p) {
                __syncthreads();   // previous LDS use complete
#pragma unroll
                for (int c = 0; c < 16; ++c)
                    smem[tid * RP + c] = acc[p * 16 + c];
                __syncthreads();
                if (tid < 256) {
                    const int c = tid >> 4;            // 0..15
                    const int b = c + p * 16;
                    float s = 0.f;
#pragma unroll
                    for (int ks = 0; ks < 32; ++ks)
                        s += smem[(jj + (ks << 4)) * RP + c];
                    const float dx   = tanhf(s + bias);
                    const float hold = __hip_atomic_load(&hrow[(size_t)b * H_ + jg],
                                                         __ATOMIC_RELAXED, __HIP_MEMORY_SCOPE_AGENT);
                    const float hn   = hold + (dx - hold) / tv;
                    __hip_atomic_store(&wl[(size_t)b * H_ + jg], hn,
                                       __ATOMIC_RELAXED, __HIP_MEMORY_SCOPE_AGENT);
                }
            }
        }

        // __syncthreads() drains every wave's vmem ops (s_waitcnt vmcnt(0)
        // before s_barrier) -> all sc1 stores at MALL before the release-add.
        __syncthreads();
        if (tid == 0)
            __hip_atomic_fetch_add(&count[tick], 1u,
                                   __ATOMIC_RELEASE, __HIP_MEMORY_SCOPE_AGENT);
    }
}

// out[b][o] = sum_k h3[b][k] * W_out[k][o] + b_out[o]   (validated rounds 0-10)
__global__ __launch_bounds__(256) void lnn_out(
    const float* __restrict__ H3,     // [B][H]
    const float* __restrict__ W_out,  // [H][O]
    const float* __restrict__ b_out,  // [O]
    float* __restrict__ out)          // [B][O]
{
    const int gid = blockIdx.x * 256 + threadIdx.x;  // 64 blocks -> 16384 threads
    const int jj  = gid & 1023;
    const int b2  = gid >> 10;                       // 0..15 -> rows b2, b2+16
    float acc0 = b_out[jj];
    float acc1 = b_out[jj];
    for (int k = 0; k < H_; ++k) {
        const float w = W_out[k * H_ + jj];
        acc0 += H3[b2 * H_ + k]        * w;
        acc1 += H3[(b2 + 16) * H_ + k] * w;
    }
    out[b2 * H_ + jj]        = acc0;
    out[(b2 + 16) * H_ + jj] = acc1;
}

extern "C" void kernel_launch(void* const* d_in, const int* in_sizes, int n_in,
                              void* d_out, int out_size, void* d_ws, size_t ws_size,
                              hipStream_t stream) {
    const float* x     = (const float*)d_in[0];
    const float* W_in  = (const float*)d_in[1];
    const float* b_in  = (const float*)d_in[2];
    const float* W_h   = (const float*)d_in[3];
    const float* b_h   = (const float*)d_in[4];
    const float* tau   = (const float*)d_in[5];
    const float* W_out = (const float*)d_in[6];
    const float* b_out = (const float*)d_in[7];

    const size_t stateElems = (size_t)L_ * B_ * H_;       // 131072 floats
    float* buf0 = (float*)d_ws;
    float* buf1 = buf0 + stateElems;
    unsigned int* count = (unsigned int*)(buf1 + stateElems);

    // zero state + lockstep counters (captured in graph -> reset every replay)
    (void)hipMemsetAsync(d_ws, 0,
                         2 * stateElems * sizeof(float) + NTICK * sizeof(unsigned int), stream);

    lnn_persist<<<256, 512, 0, stream>>>(x, W_in, b_in, W_h, b_h, tau, buf0, buf1, count);

    // h3 at t=511 computed at tick 514 -> write parity 514&1 = 0 -> buf0.
    // Kernel boundary provides coherence for these plain loads.
    const float* H3 = buf0 + 3 * (B_ * H_);
    lnn_out<<<64, 256, 0, stream>>>(H3, W_out, b_out, (float*)d_out);
}